// Round 1
// baseline (1382.442 us; speedup 1.0000x reference)
//
#include <hip/hip_runtime.h>
#include <math.h>

// ---------------------------------------------------------------------------
// GAT x3 + BN on MI355X.  Plan:
//   once per call: histogram(dst) -> exclusive scan -> counting-sort edges
//                  into Edge{src, ea0,ea1,ea2} grouped by dst; ea mean reduce.
//   per layer:     w_e = We@a_edge (3 floats) + self-loop scalar c
//                  h = X@W            (fp32 LDS-staged GEMM)
//                  al_s/al_d = h@a    (wave dot-products)
//                  fused per-node online-softmax aggregation + bias + lrelu
//                  + BN partial sums  (one wave per node, no feature atomics)
//                  BN finalize + apply (in place; y becomes next layer input)
// ---------------------------------------------------------------------------

struct __align__(16) Edge { int src; float e0, e1, e2; };

__global__ void k_hist(const int* __restrict__ dst, int E, int* __restrict__ deg) {
  int i = blockIdx.x * blockDim.x + threadIdx.x;
  if (i < E) atomicAdd(&deg[dst[i]], 1);
}

__global__ void k_ea_sum(const float* __restrict__ ea, int E, float* __restrict__ ea_sum) {
  float s0 = 0.f, s1 = 0.f, s2 = 0.f;
  for (int i = blockIdx.x * blockDim.x + threadIdx.x; i < E; i += gridDim.x * blockDim.x) {
    s0 += ea[i * 3 + 0]; s1 += ea[i * 3 + 1]; s2 += ea[i * 3 + 2];
  }
  for (int off = 32; off; off >>= 1) {
    s0 += __shfl_down(s0, off); s1 += __shfl_down(s1, off); s2 += __shfl_down(s2, off);
  }
  __shared__ float ls[3][4];
  int lane = threadIdx.x & 63, w = threadIdx.x >> 6;
  if (lane == 0) { ls[0][w] = s0; ls[1][w] = s1; ls[2][w] = s2; }
  __syncthreads();
  if (threadIdx.x == 0) {
    float t0 = 0.f, t1 = 0.f, t2 = 0.f;
    int nw = blockDim.x >> 6;
    for (int ww = 0; ww < nw; ++ww) { t0 += ls[0][ww]; t1 += ls[1][ww]; t2 += ls[2][ww]; }
    atomicAdd(&ea_sum[0], t0); atomicAdd(&ea_sum[1], t1); atomicAdd(&ea_sum[2], t2);
  }
}

// single-block exclusive scan of deg[n] -> start[n+1]
__global__ void k_scan(const int* __restrict__ deg, int* __restrict__ start, int n) {
  __shared__ int wsum[16];
  __shared__ int carry_s;
  int tid = threadIdx.x, lane = tid & 63, w = tid >> 6;
  if (tid == 0) carry_s = 0;
  __syncthreads();
  for (int base = 0; base < n; base += 1024) {
    int i = base + tid;
    int v = (i < n) ? deg[i] : 0;
    int x = v;
    for (int off = 1; off < 64; off <<= 1) {
      int t = __shfl_up(x, off);
      if (lane >= off) x += t;
    }
    if (lane == 63) wsum[w] = x;
    __syncthreads();
    if (w == 0 && lane < 16) {
      int t = wsum[lane];
      for (int off = 1; off < 16; off <<= 1) {
        int u = __shfl_up(t, off);
        if (lane >= off) t += u;
      }
      wsum[lane] = t;
    }
    __syncthreads();
    int waveoff = (w > 0) ? wsum[w - 1] : 0;
    int incl = x + waveoff;
    int carry = carry_s;
    if (i < n) start[i] = carry + incl - v;
    __syncthreads();
    if (tid == 1023) carry_s = carry + wsum[15];
    __syncthreads();
  }
  if (tid == 0) start[n] = carry_s;
}

__global__ void k_copy(const int* __restrict__ a, int* __restrict__ b, int n) {
  int i = blockIdx.x * blockDim.x + threadIdx.x;
  if (i < n) b[i] = a[i];
}

__global__ void k_scatter(const int* __restrict__ src, const int* __restrict__ dst,
                          const float* __restrict__ ea, int E,
                          int* __restrict__ cursor, Edge* __restrict__ edges) {
  int i = blockIdx.x * blockDim.x + threadIdx.x;
  if (i >= E) return;
  int d = dst[i];
  int pos = atomicAdd(&cursor[d], 1);
  Edge e;
  e.src = src[i];
  e.e0 = ea[i * 3 + 0]; e.e1 = ea[i * 3 + 1]; e.e2 = ea[i * 3 + 2];
  edges[pos] = e;
}

// per-layer tiny params: P[0..2] = We @ a_edge rows, P[3] = self-loop edge logit
__global__ void k_param(const float* __restrict__ We, const float* __restrict__ ae,
                        const float* __restrict__ ea_sum, float invE, float* __restrict__ P) {
  int lane = threadIdx.x;  // 64 threads
  float a0 = ae[lane], a1 = ae[64 + lane];
  float p0 = We[0 * 128 + lane] * a0 + We[0 * 128 + 64 + lane] * a1;
  float p1 = We[1 * 128 + lane] * a0 + We[1 * 128 + 64 + lane] * a1;
  float p2 = We[2 * 128 + lane] * a0 + We[2 * 128 + 64 + lane] * a1;
  for (int off = 32; off; off >>= 1) {
    p0 += __shfl_down(p0, off); p1 += __shfl_down(p1, off); p2 += __shfl_down(p2, off);
  }
  if (lane == 0) {
    P[0] = p0; P[1] = p1; P[2] = p2;
    P[3] = ea_sum[0] * invE * p0 + ea_sum[1] * invE * p1 + ea_sum[2] * invE * p2;
  }
}

// h[N,128] = X[N,128] @ W[128,128]; block = 256 threads covers 8 rows
__global__ __launch_bounds__(256) void k_gemm(const float* __restrict__ X,
                                              const float* __restrict__ Wm,
                                              float* __restrict__ h, int n) {
  __shared__ float xs[8 * 128];
  int t = threadIdx.x;
  int r0 = blockIdx.x * 8;
  if (r0 + 8 <= n) {
    ((float4*)xs)[t] = ((const float4*)(X + (size_t)r0 * 128))[t];
  } else {
    for (int j = t; j < 8 * 128; j += 256) {
      int rr = j >> 7;
      xs[j] = (r0 + rr < n) ? X[(size_t)(r0 + rr) * 128 + (j & 127)] : 0.f;
    }
  }
  __syncthreads();
  int c4 = (t & 31) << 2;
  int r = t >> 5;
  if (r0 + r >= n) return;
  float a0 = 0.f, a1 = 0.f, a2 = 0.f, a3 = 0.f;
  const float* xr = xs + r * 128;
#pragma unroll 8
  for (int k = 0; k < 128; ++k) {
    float xv = xr[k];
    float4 wv = *(const float4*)(Wm + k * 128 + c4);
    a0 = fmaf(xv, wv.x, a0); a1 = fmaf(xv, wv.y, a1);
    a2 = fmaf(xv, wv.z, a2); a3 = fmaf(xv, wv.w, a3);
  }
  float4 o = {a0, a1, a2, a3};
  *(float4*)(h + (size_t)(r0 + r) * 128 + c4) = o;
}

// al_s[i] = h[i]@a_src, al_d[i] = h[i]@a_dst (one wave per node, grid-stride)
__global__ __launch_bounds__(256) void k_al(const float* __restrict__ h,
                                            const float* __restrict__ as,
                                            const float* __restrict__ ad,
                                            float* __restrict__ al_s,
                                            float* __restrict__ al_d, int n) {
  int lane = threadIdx.x & 63;
  int gw = (blockIdx.x * blockDim.x + threadIdx.x) >> 6;
  int nw = (gridDim.x * blockDim.x) >> 6;
  float as0 = as[lane], as1 = as[64 + lane];
  float ad0 = ad[lane], ad1 = ad[64 + lane];
  for (int i = gw; i < n; i += nw) {
    const float* hi = h + (size_t)i * 128;
    float h0 = hi[lane], h1 = hi[64 + lane];
    float ps = h0 * as0 + h1 * as1;
    float pd = h0 * ad0 + h1 * ad1;
    for (int off = 32; off; off >>= 1) {
      ps += __shfl_down(ps, off);
      pd += __shfl_down(pd, off);
    }
    if (lane == 0) { al_s[i] = ps; al_d[i] = pd; }
  }
}

// fused: per-node online-softmax aggregation + bias + lrelu(0.01) + BN partials
__global__ __launch_bounds__(256) void k_agg(const float4* __restrict__ edges,
                                             const int* __restrict__ start,
                                             const float* __restrict__ h,
                                             const float* __restrict__ al_s,
                                             const float* __restrict__ al_d,
                                             const float* __restrict__ P,
                                             const float* __restrict__ bias,
                                             float* __restrict__ y,
                                             float* __restrict__ colsum,
                                             float* __restrict__ colsumsq, int n) {
  int lane = threadIdx.x & 63;
  int w = threadIdx.x >> 6;
  int gw = (blockIdx.x * blockDim.x + threadIdx.x) >> 6;
  int nw = (gridDim.x * blockDim.x) >> 6;
  float w0 = P[0], w1 = P[1], w2 = P[2], cself = P[3];
  float b0 = bias[lane], b1 = bias[64 + lane];
  float s0 = 0.f, s1 = 0.f, q0 = 0.f, q1 = 0.f;
  for (int i = gw; i < n; i += nw) {
    float adi = al_d[i];
    float aself = al_s[i] + adi + cself;
    aself = aself > 0.f ? aself : 0.2f * aself;
    float m = aself;
    float l = 1.0f;
    const float* hi = h + (size_t)i * 128;
    float acc0 = hi[lane], acc1 = hi[64 + lane];
    int e = start[i], eend = start[i + 1];
    for (; e < eend; ++e) {
      float4 ef = edges[e];  // broadcast 16B load
      int srcn = __float_as_int(ef.x);
      float a = al_s[srcn] + adi + (ef.y * w0 + ef.z * w1 + ef.w * w2);
      a = a > 0.f ? a : 0.2f * a;
      float mn = fmaxf(m, a);
      float sc = __expf(m - mn);
      float p = __expf(a - mn);
      const float* hs = h + (size_t)srcn * 128;
      float h0 = hs[lane], h1 = hs[64 + lane];
      l = l * sc + p;
      acc0 = fmaf(acc0, sc, p * h0);
      acc1 = fmaf(acc1, sc, p * h1);
      m = mn;
    }
    float inv = 1.0f / (l + 1e-16f);
    float o0 = fmaf(acc0, inv, b0);
    float o1 = fmaf(acc1, inv, b1);
    o0 = o0 > 0.f ? o0 : 0.01f * o0;
    o1 = o1 > 0.f ? o1 : 0.01f * o1;
    float* yi = y + (size_t)i * 128;
    yi[lane] = o0; yi[64 + lane] = o1;
    s0 += o0; s1 += o1;
    q0 = fmaf(o0, o0, q0); q1 = fmaf(o1, o1, q1);
  }
  __shared__ float red[4][4][64];
  red[0][w][lane] = s0; red[1][w][lane] = s1; red[2][w][lane] = q0; red[3][w][lane] = q1;
  __syncthreads();
  if (w == 0) {
    for (int ww = 1; ww < 4; ++ww) {
      s0 += red[0][ww][lane]; s1 += red[1][ww][lane];
      q0 += red[2][ww][lane]; q1 += red[3][ww][lane];
    }
    atomicAdd(&colsum[lane], s0);
    atomicAdd(&colsum[64 + lane], s1);
    atomicAdd(&colsumsq[lane], q0);
    atomicAdd(&colsumsq[64 + lane], q1);
  }
}

__global__ void k_bnfinal(const float* __restrict__ colsum, const float* __restrict__ colsumsq,
                          const float* __restrict__ g, const float* __restrict__ be,
                          float invN, float* __restrict__ scale, float* __restrict__ shift) {
  int c = threadIdx.x;  // 128
  float mu = colsum[c] * invN;
  float var = colsumsq[c] * invN - mu * mu;
  var = var > 0.f ? var : 0.f;
  float sc = g[c] * rsqrtf(var + 1e-5f);
  scale[c] = sc;
  shift[c] = be[c] - mu * sc;
}

__global__ void k_bnapply(const float4* __restrict__ yin, const float* __restrict__ scale,
                          const float* __restrict__ shift, float4* __restrict__ yout, int total4) {
  int i = blockIdx.x * blockDim.x + threadIdx.x;
  if (i >= total4) return;
  int c4 = i & 31;
  float4 v = yin[i];
  float4 sc = ((const float4*)scale)[c4];
  float4 sh = ((const float4*)shift)[c4];
  v.x = fmaf(v.x, sc.x, sh.x);
  v.y = fmaf(v.y, sc.y, sh.y);
  v.z = fmaf(v.z, sc.z, sh.z);
  v.w = fmaf(v.w, sc.w, sh.w);
  yout[i] = v;
}

extern "C" void kernel_launch(void* const* d_in, const int* in_sizes, int n_in,
                              void* d_out, int out_size, void* d_ws, size_t ws_size,
                              hipStream_t stream) {
  const float* x = (const float*)d_in[0];
  const int* eidx = (const int*)d_in[1];
  const float* ea = (const float*)d_in[3];
  const int H = 128;
  const int N = in_sizes[0] / H;
  const int E = in_sizes[1] / 2;
  const int* srcIdx = eidx;
  const int* dstIdx = eidx + E;

  char* ws = (char*)d_ws;
  size_t off = 0;
  auto alloc = [&](size_t bytes) -> void* {
    void* p = ws + off;
    off = (off + bytes + 255) & ~(size_t)255;
    return p;
  };
  Edge* edges = (Edge*)alloc((size_t)E * sizeof(Edge));
  float* h = (float*)alloc((size_t)N * H * sizeof(float));
  float* y = (float*)alloc((size_t)N * H * sizeof(float));
  float* al_s = (float*)alloc((size_t)N * sizeof(float));
  float* al_d = (float*)alloc((size_t)N * sizeof(float));
  int* deg = (int*)alloc((size_t)N * sizeof(int));
  int* start = (int*)alloc((size_t)(N + 1) * sizeof(int));
  int* cursor = (int*)alloc((size_t)N * sizeof(int));
  float* colsum = (float*)alloc(128 * sizeof(float));
  float* colsumsq = (float*)alloc(128 * sizeof(float));
  float* scale = (float*)alloc(128 * sizeof(float));
  float* shift = (float*)alloc(128 * sizeof(float));
  float* ea_sum = (float*)alloc(16 * sizeof(float));
  float* P = (float*)alloc(16 * sizeof(float));

  // ---- once per call: sort edges by destination ----
  hipMemsetAsync(deg, 0, (size_t)N * sizeof(int), stream);
  hipMemsetAsync(ea_sum, 0, 16 * sizeof(float), stream);
  k_hist<<<(E + 255) / 256, 256, 0, stream>>>(dstIdx, E, deg);
  k_ea_sum<<<256, 256, 0, stream>>>(ea, E, ea_sum);
  k_scan<<<1, 1024, 0, stream>>>(deg, start, N);
  k_copy<<<(N + 255) / 256, 256, 0, stream>>>(start, cursor, N);
  k_scatter<<<(E + 255) / 256, 256, 0, stream>>>(srcIdx, dstIdx, ea, E, cursor, edges);

  const float* X = x;
  for (int l = 0; l < 3; ++l) {
    const float* W = (const float*)d_in[4 + 8 * l + 0];
    const float* as = (const float*)d_in[4 + 8 * l + 1];
    const float* ad = (const float*)d_in[4 + 8 * l + 2];
    const float* We = (const float*)d_in[4 + 8 * l + 3];
    const float* ae = (const float*)d_in[4 + 8 * l + 4];
    const float* b = (const float*)d_in[4 + 8 * l + 5];
    const float* g = (const float*)d_in[4 + 8 * l + 6];
    const float* be = (const float*)d_in[4 + 8 * l + 7];

    hipMemsetAsync(colsum, 0, 128 * sizeof(float), stream);
    hipMemsetAsync(colsumsq, 0, 128 * sizeof(float), stream);
    k_param<<<1, 64, 0, stream>>>(We, ae, ea_sum, 1.0f / (float)E, P);
    k_gemm<<<(N + 7) / 8, 256, 0, stream>>>(X, W, h, N);
    k_al<<<512, 256, 0, stream>>>(h, as, ad, al_s, al_d, N);
    k_agg<<<512, 256, 0, stream>>>((const float4*)edges, start, h, al_s, al_d, P, b, y,
                                   colsum, colsumsq, N);
    k_bnfinal<<<1, 128, 0, stream>>>(colsum, colsumsq, g, be, 1.0f / (float)N, scale, shift);
    float* outp = (l == 2) ? (float*)d_out : y;
    k_bnapply<<<((N * 32) + 255) / 256, 256, 0, stream>>>((const float4*)y, scale, shift,
                                                          (float4*)outp, N * 32);
    X = y;
  }
}

// Round 2
// 1144.989 us; speedup vs baseline: 1.2074x; 1.2074x over previous
//
#include <hip/hip_runtime.h>
#include <math.h>

// ---------------------------------------------------------------------------
// GAT x3 + BN on MI355X.
//   once per call: histogram(dst) -> exclusive scan -> counting-sort edges
//                  (Edge{src,ea0..2} + srcs[] + dsts[]) grouped by dst.
//   per layer:     P = We@a_edge (3 floats) + self-loop logit
//                  h = X@W                       (fp32 GEMM)
//                  al_s/al_d = h@a               (wave dot products)
//                  alpha[e] = lrelu(als+ald+ale) (flat per-edge, parallel)
//                  k_agg2: per-node exact softmax, lane-parallel max/sum,
//                          shuffle-broadcast accumulate + bias + lrelu + BN
//                  BN finalize + apply
// Round 2: broke k_agg's serial online-softmax chain (was 1500 cyc/edge,
// latency-bound at 21% occupancy) into flat alpha + lane-parallel two-pass
// softmax; grid 512->2048 blocks for 32 waves/CU.
// ---------------------------------------------------------------------------

struct __align__(16) Edge { int src; float e0, e1, e2; };

__global__ void k_hist(const int* __restrict__ dst, int E, int* __restrict__ deg) {
  int i = blockIdx.x * blockDim.x + threadIdx.x;
  if (i < E) atomicAdd(&deg[dst[i]], 1);
}

__global__ void k_ea_sum(const float* __restrict__ ea, int E, float* __restrict__ ea_sum) {
  float s0 = 0.f, s1 = 0.f, s2 = 0.f;
  for (int i = blockIdx.x * blockDim.x + threadIdx.x; i < E; i += gridDim.x * blockDim.x) {
    s0 += ea[i * 3 + 0]; s1 += ea[i * 3 + 1]; s2 += ea[i * 3 + 2];
  }
  for (int off = 32; off; off >>= 1) {
    s0 += __shfl_down(s0, off); s1 += __shfl_down(s1, off); s2 += __shfl_down(s2, off);
  }
  __shared__ float ls[3][4];
  int lane = threadIdx.x & 63, w = threadIdx.x >> 6;
  if (lane == 0) { ls[0][w] = s0; ls[1][w] = s1; ls[2][w] = s2; }
  __syncthreads();
  if (threadIdx.x == 0) {
    float t0 = 0.f, t1 = 0.f, t2 = 0.f;
    int nw = blockDim.x >> 6;
    for (int ww = 0; ww < nw; ++ww) { t0 += ls[0][ww]; t1 += ls[1][ww]; t2 += ls[2][ww]; }
    atomicAdd(&ea_sum[0], t0); atomicAdd(&ea_sum[1], t1); atomicAdd(&ea_sum[2], t2);
  }
}

// single-block exclusive scan of deg[n] -> start[n+1]
__global__ void k_scan(const int* __restrict__ deg, int* __restrict__ start, int n) {
  __shared__ int wsum[16];
  __shared__ int carry_s;
  int tid = threadIdx.x, lane = tid & 63, w = tid >> 6;
  if (tid == 0) carry_s = 0;
  __syncthreads();
  for (int base = 0; base < n; base += 1024) {
    int i = base + tid;
    int v = (i < n) ? deg[i] : 0;
    int x = v;
    for (int off = 1; off < 64; off <<= 1) {
      int t = __shfl_up(x, off);
      if (lane >= off) x += t;
    }
    if (lane == 63) wsum[w] = x;
    __syncthreads();
    if (w == 0 && lane < 16) {
      int t = wsum[lane];
      for (int off = 1; off < 16; off <<= 1) {
        int u = __shfl_up(t, off);
        if (lane >= off) t += u;
      }
      wsum[lane] = t;
    }
    __syncthreads();
    int waveoff = (w > 0) ? wsum[w - 1] : 0;
    int incl = x + waveoff;
    int carry = carry_s;
    if (i < n) start[i] = carry + incl - v;
    __syncthreads();
    if (tid == 1023) carry_s = carry + wsum[15];
    __syncthreads();
  }
  if (tid == 0) start[n] = carry_s;
}

__global__ void k_copy(const int* __restrict__ a, int* __restrict__ b, int n) {
  int i = blockIdx.x * blockDim.x + threadIdx.x;
  if (i < n) b[i] = a[i];
}

__global__ void k_scatter(const int* __restrict__ src, const int* __restrict__ dst,
                          const float* __restrict__ ea, int E,
                          int* __restrict__ cursor, Edge* __restrict__ edges,
                          int* __restrict__ srcs, int* __restrict__ dsts) {
  int i = blockIdx.x * blockDim.x + threadIdx.x;
  if (i >= E) return;
  int d = dst[i];
  int pos = atomicAdd(&cursor[d], 1);
  Edge e;
  int s = src[i];
  e.src = s;
  e.e0 = ea[i * 3 + 0]; e.e1 = ea[i * 3 + 1]; e.e2 = ea[i * 3 + 2];
  edges[pos] = e;
  srcs[pos] = s;
  dsts[pos] = d;
}

// per-layer tiny params: P[0..2] = We @ a_edge rows, P[3] = self-loop edge logit
__global__ void k_param(const float* __restrict__ We, const float* __restrict__ ae,
                        const float* __restrict__ ea_sum, float invE, float* __restrict__ P) {
  int lane = threadIdx.x;  // 64 threads
  float a0 = ae[lane], a1 = ae[64 + lane];
  float p0 = We[0 * 128 + lane] * a0 + We[0 * 128 + 64 + lane] * a1;
  float p1 = We[1 * 128 + lane] * a0 + We[1 * 128 + 64 + lane] * a1;
  float p2 = We[2 * 128 + lane] * a0 + We[2 * 128 + 64 + lane] * a1;
  for (int off = 32; off; off >>= 1) {
    p0 += __shfl_down(p0, off); p1 += __shfl_down(p1, off); p2 += __shfl_down(p2, off);
  }
  if (lane == 0) {
    P[0] = p0; P[1] = p1; P[2] = p2;
    P[3] = ea_sum[0] * invE * p0 + ea_sum[1] * invE * p1 + ea_sum[2] * invE * p2;
  }
}

// h[N,128] = X[N,128] @ W[128,128]; block = 256 threads covers 8 rows
__global__ __launch_bounds__(256) void k_gemm(const float* __restrict__ X,
                                              const float* __restrict__ Wm,
                                              float* __restrict__ h, int n) {
  __shared__ float xs[8 * 128];
  int t = threadIdx.x;
  int r0 = blockIdx.x * 8;
  if (r0 + 8 <= n) {
    ((float4*)xs)[t] = ((const float4*)(X + (size_t)r0 * 128))[t];
  } else {
    for (int j = t; j < 8 * 128; j += 256) {
      int rr = j >> 7;
      xs[j] = (r0 + rr < n) ? X[(size_t)(r0 + rr) * 128 + (j & 127)] : 0.f;
    }
  }
  __syncthreads();
  int c4 = (t & 31) << 2;
  int r = t >> 5;
  if (r0 + r >= n) return;
  float a0 = 0.f, a1 = 0.f, a2 = 0.f, a3 = 0.f;
  const float* xr = xs + r * 128;
#pragma unroll 8
  for (int k = 0; k < 128; ++k) {
    float xv = xr[k];
    float4 wv = *(const float4*)(Wm + k * 128 + c4);
    a0 = fmaf(xv, wv.x, a0); a1 = fmaf(xv, wv.y, a1);
    a2 = fmaf(xv, wv.z, a2); a3 = fmaf(xv, wv.w, a3);
  }
  float4 o = {a0, a1, a2, a3};
  *(float4*)(h + (size_t)(r0 + r) * 128 + c4) = o;
}

// al_s[i] = h[i]@a_src, al_d[i] = h[i]@a_dst (one wave per node, grid-stride)
__global__ __launch_bounds__(256) void k_al(const float* __restrict__ h,
                                            const float* __restrict__ as,
                                            const float* __restrict__ ad,
                                            float* __restrict__ al_s,
                                            float* __restrict__ al_d, int n) {
  int lane = threadIdx.x & 63;
  int gw = (blockIdx.x * blockDim.x + threadIdx.x) >> 6;
  int nw = (gridDim.x * blockDim.x) >> 6;
  float2 a2s = ((const float2*)as)[lane];
  float2 a2d = ((const float2*)ad)[lane];
  for (int i = gw; i < n; i += nw) {
    float2 h2 = ((const float2*)(h + (size_t)i * 128))[lane];
    float ps = h2.x * a2s.x + h2.y * a2s.y;
    float pd = h2.x * a2d.x + h2.y * a2d.y;
    for (int off = 32; off; off >>= 1) {
      ps += __shfl_down(ps, off);
      pd += __shfl_down(pd, off);
    }
    if (lane == 0) { al_s[i] = ps; al_d[i] = pd; }
  }
}

// flat per-edge logits: alpha[e] = lrelu_0.2(al_s[src] + al_d[dst] + ea.w)
__global__ __launch_bounds__(256) void k_alpha(const float4* __restrict__ edges,
                                               const int* __restrict__ dsts,
                                               const float* __restrict__ al_s,
                                               const float* __restrict__ al_d,
                                               const float* __restrict__ P,
                                               float* __restrict__ alpha, int E) {
  int i = blockIdx.x * blockDim.x + threadIdx.x;
  if (i >= E) return;
  float4 ef = edges[i];
  int s = __float_as_int(ef.x);
  float a = al_s[s] + al_d[dsts[i]] + ef.y * P[0] + ef.z * P[1] + ef.w * P[2];
  alpha[i] = a > 0.f ? a : 0.2f * a;
}

// per-node exact softmax + aggregate + bias + lrelu(0.01) + BN partials.
// One wave per node; lanes parallel over edges for max/denom, parallel over
// features (2/lane, float2) for accumulate with shuffle-broadcast of (p,src).
__global__ __launch_bounds__(256) void k_agg2(const int* __restrict__ srcs,
                                              const float* __restrict__ alpha,
                                              const int* __restrict__ start,
                                              const float* __restrict__ h,
                                              const float* __restrict__ al_s,
                                              const float* __restrict__ al_d,
                                              const float* __restrict__ P,
                                              const float* __restrict__ bias,
                                              float* __restrict__ y,
                                              float* __restrict__ colsum,
                                              float* __restrict__ colsumsq, int n) {
  int lane = threadIdx.x & 63;
  int w = threadIdx.x >> 6;
  int gw = (blockIdx.x * blockDim.x + threadIdx.x) >> 6;
  int nw = (gridDim.x * blockDim.x) >> 6;
  float cself = P[3];
  float2 b2 = ((const float2*)bias)[lane];
  float s0 = 0.f, s1 = 0.f, q0 = 0.f, q1 = 0.f;  // BN partials
  for (int i = gw; i < n; i += nw) {
    int e0 = start[i];
    int deg = start[i + 1] - e0;
    float aself = al_s[i] + al_d[i] + cself;
    aself = aself > 0.f ? aself : 0.2f * aself;
    // pass 1: max over edge logits (lane-parallel)
    float mx = aself;
    for (int j = lane; j < deg; j += 64) mx = fmaxf(mx, alpha[e0 + j]);
    for (int off = 32; off; off >>= 1) mx = fmaxf(mx, __shfl_xor(mx, off));
    // pass 2: exp + accumulate
    float es = __expf(aself - mx);
    float2 h2 = ((const float2*)(h + (size_t)i * 128))[lane];
    float acc0 = es * h2.x, acc1 = es * h2.y;
    float pacc = 0.f;
    for (int base = 0; base < deg; base += 64) {
      int j = base + lane;
      float p = 0.f; int sidx = 0;
      if (j < deg) {
        p = __expf(alpha[e0 + j] - mx);
        sidx = srcs[e0 + j];
      }
      pacc += p;
      int cnt = deg - base; if (cnt > 64) cnt = 64;
      for (int t = 0; t < cnt; ++t) {
        float pt = __shfl(p, t);
        int st = __shfl(sidx, t);
        float2 hs = ((const float2*)(h + (size_t)st * 128))[lane];
        acc0 = fmaf(pt, hs.x, acc0);
        acc1 = fmaf(pt, hs.y, acc1);
      }
    }
    for (int off = 32; off; off >>= 1) pacc += __shfl_xor(pacc, off);
    float inv = 1.0f / (es + pacc + 1e-16f);
    float o0 = fmaf(acc0, inv, b2.x);
    float o1 = fmaf(acc1, inv, b2.y);
    o0 = o0 > 0.f ? o0 : 0.01f * o0;
    o1 = o1 > 0.f ? o1 : 0.01f * o1;
    float2 o2 = {o0, o1};
    ((float2*)(y + (size_t)i * 128))[lane] = o2;
    s0 += o0; s1 += o1;
    q0 = fmaf(o0, o0, q0); q1 = fmaf(o1, o1, q1);
  }
  __shared__ float red[4][4][64];
  red[0][w][lane] = s0; red[1][w][lane] = s1; red[2][w][lane] = q0; red[3][w][lane] = q1;
  __syncthreads();
  if (w == 0) {
    for (int ww = 1; ww < 4; ++ww) {
      s0 += red[0][ww][lane]; s1 += red[1][ww][lane];
      q0 += red[2][ww][lane]; q1 += red[3][ww][lane];
    }
    atomicAdd(&colsum[2 * lane], s0);
    atomicAdd(&colsum[2 * lane + 1], s1);
    atomicAdd(&colsumsq[2 * lane], q0);
    atomicAdd(&colsumsq[2 * lane + 1], q1);
  }
}

__global__ void k_bnfinal(const float* __restrict__ colsum, const float* __restrict__ colsumsq,
                          const float* __restrict__ g, const float* __restrict__ be,
                          float invN, float* __restrict__ scale, float* __restrict__ shift) {
  int c = threadIdx.x;  // 128
  float mu = colsum[c] * invN;
  float var = colsumsq[c] * invN - mu * mu;
  var = var > 0.f ? var : 0.f;
  float sc = g[c] * rsqrtf(var + 1e-5f);
  scale[c] = sc;
  shift[c] = be[c] - mu * sc;
}

__global__ void k_bnapply(const float4* __restrict__ yin, const float* __restrict__ scale,
                          const float* __restrict__ shift, float4* __restrict__ yout, int total4) {
  int i = blockIdx.x * blockDim.x + threadIdx.x;
  if (i >= total4) return;
  int c4 = i & 31;
  float4 v = yin[i];
  float4 sc = ((const float4*)scale)[c4];
  float4 sh = ((const float4*)shift)[c4];
  v.x = fmaf(v.x, sc.x, sh.x);
  v.y = fmaf(v.y, sc.y, sh.y);
  v.z = fmaf(v.z, sc.z, sh.z);
  v.w = fmaf(v.w, sc.w, sh.w);
  yout[i] = v;
}

extern "C" void kernel_launch(void* const* d_in, const int* in_sizes, int n_in,
                              void* d_out, int out_size, void* d_ws, size_t ws_size,
                              hipStream_t stream) {
  const float* x = (const float*)d_in[0];
  const int* eidx = (const int*)d_in[1];
  const float* ea = (const float*)d_in[3];
  const int H = 128;
  const int N = in_sizes[0] / H;
  const int E = in_sizes[1] / 2;
  const int* srcIdx = eidx;
  const int* dstIdx = eidx + E;

  char* ws = (char*)d_ws;
  size_t off = 0;
  auto alloc = [&](size_t bytes) -> void* {
    void* p = ws + off;
    off = (off + bytes + 255) & ~(size_t)255;
    return p;
  };
  Edge* edges = (Edge*)alloc((size_t)E * sizeof(Edge));
  int* srcs = (int*)alloc((size_t)E * sizeof(int));
  int* dsts = (int*)alloc((size_t)E * sizeof(int));
  float* alpha = (float*)alloc((size_t)E * sizeof(float));
  float* h = (float*)alloc((size_t)N * H * sizeof(float));
  float* y = (float*)alloc((size_t)N * H * sizeof(float));
  float* al_s = (float*)alloc((size_t)N * sizeof(float));
  float* al_d = (float*)alloc((size_t)N * sizeof(float));
  int* deg = (int*)alloc((size_t)N * sizeof(int));
  int* start = (int*)alloc((size_t)(N + 1) * sizeof(int));
  int* cursor = (int*)alloc((size_t)N * sizeof(int));
  float* colsum = (float*)alloc(128 * sizeof(float));
  float* colsumsq = (float*)alloc(128 * sizeof(float));
  float* scale = (float*)alloc(128 * sizeof(float));
  float* shift = (float*)alloc(128 * sizeof(float));
  float* ea_sum = (float*)alloc(16 * sizeof(float));
  float* P = (float*)alloc(16 * sizeof(float));

  // ---- once per call: sort edges by destination ----
  hipMemsetAsync(deg, 0, (size_t)N * sizeof(int), stream);
  hipMemsetAsync(ea_sum, 0, 16 * sizeof(float), stream);
  k_hist<<<(E + 255) / 256, 256, 0, stream>>>(dstIdx, E, deg);
  k_ea_sum<<<256, 256, 0, stream>>>(ea, E, ea_sum);
  k_scan<<<1, 1024, 0, stream>>>(deg, start, N);
  k_copy<<<(N + 255) / 256, 256, 0, stream>>>(start, cursor, N);
  k_scatter<<<(E + 255) / 256, 256, 0, stream>>>(srcIdx, dstIdx, ea, E, cursor, edges, srcs, dsts);

  const float* X = x;
  for (int l = 0; l < 3; ++l) {
    const float* W = (const float*)d_in[4 + 8 * l + 0];
    const float* as = (const float*)d_in[4 + 8 * l + 1];
    const float* ad = (const float*)d_in[4 + 8 * l + 2];
    const float* We = (const float*)d_in[4 + 8 * l + 3];
    const float* ae = (const float*)d_in[4 + 8 * l + 4];
    const float* b = (const float*)d_in[4 + 8 * l + 5];
    const float* g = (const float*)d_in[4 + 8 * l + 6];
    const float* be = (const float*)d_in[4 + 8 * l + 7];

    hipMemsetAsync(colsum, 0, 128 * sizeof(float), stream);
    hipMemsetAsync(colsumsq, 0, 128 * sizeof(float), stream);
    k_param<<<1, 64, 0, stream>>>(We, ae, ea_sum, 1.0f / (float)E, P);
    k_gemm<<<(N + 7) / 8, 256, 0, stream>>>(X, W, h, N);
    k_al<<<512, 256, 0, stream>>>(h, as, ad, al_s, al_d, N);
    k_alpha<<<(E + 255) / 256, 256, 0, stream>>>((const float4*)edges, dsts, al_s, al_d, P,
                                                 alpha, E);
    k_agg2<<<2048, 256, 0, stream>>>(srcs, alpha, start, h, al_s, al_d, P, b, y,
                                     colsum, colsumsq, N);
    k_bnfinal<<<1, 128, 0, stream>>>(colsum, colsumsq, g, be, 1.0f / (float)N, scale, shift);
    float* outp = (l == 2) ? (float*)d_out : y;
    k_bnapply<<<((N * 32) + 255) / 256, 256, 0, stream>>>((const float4*)y, scale, shift,
                                                          (float4*)outp, N * 32);
    X = y;
  }
}

// Round 3
// 850.182 us; speedup vs baseline: 1.6261x; 1.3468x over previous
//
#include <hip/hip_runtime.h>
#include <math.h>

// ---------------------------------------------------------------------------
// GAT x3 + BN on MI355X.
//   setup:  hist(dst) -> 3-phase parallel scan -> counting-sort edges (CSR).
//   layer:  P = We@a_edge + self logit
//           k_gemm2: h = BN(X)@W  (W in LDS, 4x4 reg tile, fused al_s/al_d/es)
//           k_alpha2: p[e] = exp(lrelu(als[src]+ald[dst]+ale))  (no seg-max:
//                     |logit| <~ 11, exp-safe in fp32, identical result)
//           k_agg3: per-node 1-pass aggregate, 4-way unrolled shuffle-
//                   broadcast gathers (4 loads in flight), + bias+lrelu+BN
//           k_bnfinal -> scale/shift consumed by NEXT layer's gemm staging;
//           k_bnapply only for the final output.
// R3: k_agg 250->159 by breaking serial online-softmax; this round removes
// max-pass + exp from agg hot loop, 4x gather ILP, gemm W-in-LDS, BN fusion.
// ---------------------------------------------------------------------------

struct __align__(16) Edge { int src; float e0, e1, e2; };

__global__ void k_hist(const int* __restrict__ dst, int E, int* __restrict__ deg) {
  int i = blockIdx.x * blockDim.x + threadIdx.x;
  if (i < E) atomicAdd(&deg[dst[i]], 1);
}

__global__ void k_ea_sum(const float* __restrict__ ea, int E, float* __restrict__ ea_sum) {
  float s0 = 0.f, s1 = 0.f, s2 = 0.f;
  for (int i = blockIdx.x * blockDim.x + threadIdx.x; i < E; i += gridDim.x * blockDim.x) {
    s0 += ea[i * 3 + 0]; s1 += ea[i * 3 + 1]; s2 += ea[i * 3 + 2];
  }
  for (int off = 32; off; off >>= 1) {
    s0 += __shfl_down(s0, off); s1 += __shfl_down(s1, off); s2 += __shfl_down(s2, off);
  }
  __shared__ float ls[3][4];
  int lane = threadIdx.x & 63, w = threadIdx.x >> 6;
  if (lane == 0) { ls[0][w] = s0; ls[1][w] = s1; ls[2][w] = s2; }
  __syncthreads();
  if (threadIdx.x == 0) {
    float t0 = 0.f, t1 = 0.f, t2 = 0.f;
    for (int ww = 0; ww < 4; ++ww) { t0 += ls[0][ww]; t1 += ls[1][ww]; t2 += ls[2][ww]; }
    atomicAdd(&ea_sum[0], t0); atomicAdd(&ea_sum[1], t1); atomicAdd(&ea_sum[2], t2);
  }
}

__device__ __forceinline__ int wave_incl_scan(int x, int lane) {
  for (int off = 1; off < 64; off <<= 1) {
    int t = __shfl_up(x, off);
    if (lane >= off) x += t;
  }
  return x;
}

// phase A: per-block (1024 elems) exclusive scan -> start[], block sums -> bsum[]
__global__ __launch_bounds__(1024) void k_scan_a(const int* __restrict__ deg, int n,
                                                 int* __restrict__ start,
                                                 int* __restrict__ bsum) {
  __shared__ int wsum[16];
  int t = threadIdx.x, lane = t & 63, w = t >> 6;
  int i = blockIdx.x * 1024 + t;
  int v = (i < n) ? deg[i] : 0;
  int x = wave_incl_scan(v, lane);
  if (lane == 63) wsum[w] = x;
  __syncthreads();
  if (w == 0 && lane < 16) {
    int s = wsum[lane];
    for (int off = 1; off < 16; off <<= 1) {
      int u = __shfl_up(s, off);
      if (lane >= off) s += u;
    }
    wsum[lane] = s;
  }
  __syncthreads();
  int woff = w ? wsum[w - 1] : 0;
  if (i < n) start[i] = x - v + woff;
  if (t == 1023) bsum[blockIdx.x] = wsum[15];
}

// phase B: scan block sums (nb <= 64), write total to start[n]
__global__ void k_scan_b(int* __restrict__ bsum, int nb, int* __restrict__ start, int n) {
  int lane = threadIdx.x;  // 64
  int v = (lane < nb) ? bsum[lane] : 0;
  int x = wave_incl_scan(v, lane);
  if (lane < nb) bsum[lane] = x - v;
  if (lane == nb - 1) start[n] = x;
}

// phase C: add block offsets; also init cursor
__global__ void k_scan_c(int* __restrict__ start, const int* __restrict__ bsum, int n,
                         int* __restrict__ cursor) {
  int i = blockIdx.x * blockDim.x + threadIdx.x;
  if (i < n) {
    int s = start[i] + bsum[i >> 10];
    start[i] = s;
    cursor[i] = s;
  }
}

__global__ void k_scatter(const int* __restrict__ src, const int* __restrict__ dst,
                          const float* __restrict__ ea, int E,
                          int* __restrict__ cursor, Edge* __restrict__ edges,
                          int* __restrict__ srcs, int* __restrict__ dsts) {
  int i = blockIdx.x * blockDim.x + threadIdx.x;
  if (i >= E) return;
  int d = dst[i];
  int pos = atomicAdd(&cursor[d], 1);
  Edge e;
  int s = src[i];
  e.src = s;
  e.e0 = ea[i * 3 + 0]; e.e1 = ea[i * 3 + 1]; e.e2 = ea[i * 3 + 2];
  edges[pos] = e;
  srcs[pos] = s;
  dsts[pos] = d;
}

__global__ void k_initid(float* __restrict__ sc, float* __restrict__ sh) {
  int c = threadIdx.x;  // 128
  sc[c] = 1.f; sh[c] = 0.f;
}

// P[0..2] = We @ a_edge rows, P[3] = self-loop edge logit (mean edge_attr)
__global__ void k_param(const float* __restrict__ We, const float* __restrict__ ae,
                        const float* __restrict__ ea_sum, float invE, float* __restrict__ P) {
  int lane = threadIdx.x;  // 64
  float a0 = ae[lane], a1 = ae[64 + lane];
  float p0 = We[0 * 128 + lane] * a0 + We[0 * 128 + 64 + lane] * a1;
  float p1 = We[1 * 128 + lane] * a0 + We[1 * 128 + 64 + lane] * a1;
  float p2 = We[2 * 128 + lane] * a0 + We[2 * 128 + 64 + lane] * a1;
  for (int off = 32; off; off >>= 1) {
    p0 += __shfl_down(p0, off); p1 += __shfl_down(p1, off); p2 += __shfl_down(p2, off);
  }
  if (lane == 0) {
    P[0] = p0; P[1] = p1; P[2] = p2;
    P[3] = ea_sum[0] * invE * p0 + ea_sum[1] * invE * p1 + ea_sum[2] * invE * p2;
  }
}

// h[N,128] = (X*bnsc+bnsh) @ W.  W (64KB) in LDS, 32-row tiles, 4 rows x 4
// cols per thread.  Fused epilogue: al_s/al_d dot products + es = exp(self).
__global__ __launch_bounds__(256) void k_gemm2(
    const float* __restrict__ X, const float* __restrict__ Wm,
    const float* __restrict__ bnsc, const float* __restrict__ bnsh,
    const float* __restrict__ as, const float* __restrict__ ad,
    const float* __restrict__ P,
    float* __restrict__ h, float* __restrict__ al_s, float* __restrict__ al_d,
    float* __restrict__ es, int n) {
  __shared__ float wl[128 * 128];
  __shared__ float xs[32 * 128];
  int t = threadIdx.x;
  for (int i = t; i < 4096; i += 256) ((float4*)wl)[i] = ((const float4*)Wm)[i];
  int c32 = t & 31;
  int c4 = c32 << 2;
  int rq = t >> 5;  // 0..7 -> rows rq*4 .. rq*4+3
  int lane = t & 63;
  float4 av_s = *(const float4*)(as + c4);
  float4 av_d = *(const float4*)(ad + c4);
  float cself = P[3];
  int ntiles = (n + 31) >> 5;
  for (int tile = blockIdx.x; tile < ntiles; tile += gridDim.x) {
    int r0 = tile << 5;
    __syncthreads();  // xs reuse + (first iter) W staged
    for (int i = t; i < 1024; i += 256) {
      int rr = i >> 5, cc = i & 31;
      int g = r0 + rr;
      float4 v;
      if (g < n) {
        v = ((const float4*)(X + (size_t)g * 128))[cc];
        float4 sc = ((const float4*)bnsc)[cc];
        float4 sh = ((const float4*)bnsh)[cc];
        v.x = fmaf(v.x, sc.x, sh.x); v.y = fmaf(v.y, sc.y, sh.y);
        v.z = fmaf(v.z, sc.z, sh.z); v.w = fmaf(v.w, sc.w, sh.w);
      } else { v.x = v.y = v.z = v.w = 0.f; }
      ((float4*)xs)[i] = v;
    }
    __syncthreads();
    float4 acc[4];
    for (int r = 0; r < 4; ++r) { acc[r].x = acc[r].y = acc[r].z = acc[r].w = 0.f; }
    const float* xr = xs + (rq << 2) * 128;
#pragma unroll 4
    for (int k = 0; k < 128; ++k) {
      float4 w4 = ((const float4*)wl)[(k << 5) + c32];
#pragma unroll
      for (int r = 0; r < 4; ++r) {
        float xv = xr[r * 128 + k];
        acc[r].x = fmaf(xv, w4.x, acc[r].x);
        acc[r].y = fmaf(xv, w4.y, acc[r].y);
        acc[r].z = fmaf(xv, w4.z, acc[r].z);
        acc[r].w = fmaf(xv, w4.w, acc[r].w);
      }
    }
    int gbase = r0 + (rq << 2);
#pragma unroll
    for (int r = 0; r < 4; ++r) {
      int g = gbase + r;
      float4 o = acc[r];
      if (g < n) *(float4*)(h + (size_t)g * 128 + c4) = o;
      float ps = o.x * av_s.x + o.y * av_s.y + o.z * av_s.z + o.w * av_s.w;
      float pd = o.x * av_d.x + o.y * av_d.y + o.z * av_d.z + o.w * av_d.w;
      for (int off = 16; off; off >>= 1) {
        ps += __shfl_xor(ps, off);
        pd += __shfl_xor(pd, off);
      }
      if ((lane & 31) == 0 && g < n) {
        al_s[g] = ps; al_d[g] = pd;
        float a = ps + pd + cself;
        a = a > 0.f ? a : 0.2f * a;
        es[g] = __expf(a);
      }
    }
  }
}

// flat per-edge: p[e] = exp(lrelu_0.2(al_s[src] + al_d[dst] + ea.We@ae))
__global__ __launch_bounds__(256) void k_alpha2(const float4* __restrict__ edges,
                                                const int* __restrict__ dsts,
                                                const float* __restrict__ al_s,
                                                const float* __restrict__ al_d,
                                                const float* __restrict__ P,
                                                float* __restrict__ pexp, int E) {
  int i = blockIdx.x * blockDim.x + threadIdx.x;
  if (i >= E) return;
  float4 ef = edges[i];
  int s = __float_as_int(ef.x);
  float a = al_s[s] + al_d[dsts[i]] + ef.y * P[0] + ef.z * P[1] + ef.w * P[2];
  a = a > 0.f ? a : 0.2f * a;
  pexp[i] = __expf(a);
}

// one wave per node: denom sum + 4-way-unrolled broadcast gather accumulate,
// bias + lrelu(0.01) + BN partials.  No exp/max in hot loop.
__global__ __launch_bounds__(256) void k_agg3(const int* __restrict__ srcs,
                                              const float* __restrict__ pexp,
                                              const int* __restrict__ start,
                                              const float* __restrict__ h,
                                              const float* __restrict__ es,
                                              const float* __restrict__ bias,
                                              float* __restrict__ y,
                                              float* __restrict__ colsum,
                                              float* __restrict__ colsumsq, int n) {
  int lane = threadIdx.x & 63;
  int w = threadIdx.x >> 6;
  int gw = (blockIdx.x * blockDim.x + threadIdx.x) >> 6;
  int nw = (gridDim.x * blockDim.x) >> 6;
  float2 b2 = ((const float2*)bias)[lane];
  float s0 = 0.f, s1 = 0.f, q0 = 0.f, q1 = 0.f;
  for (int i = gw; i < n; i += nw) {
    int e0 = start[i];
    int deg = start[i + 1] - e0;
    float eself = es[i];
    float2 h2 = ((const float2*)(h + (size_t)i * 128))[lane];
    float accA0 = eself * h2.x, accA1 = eself * h2.y;
    float accB0 = 0.f, accB1 = 0.f, accC0 = 0.f, accC1 = 0.f, accD0 = 0.f, accD1 = 0.f;
    float pacc = 0.f;
    for (int base = 0; base < deg; base += 64) {
      int j = base + lane;
      float p = 0.f; int sidx = 0;
      if (j < deg) { p = pexp[e0 + j]; sidx = srcs[e0 + j]; }
      pacc += p;
      int cnt = deg - base; if (cnt > 64) cnt = 64;
      int tt = 0;
      for (; tt + 4 <= cnt; tt += 4) {
        float pa = __shfl(p, tt),     pb = __shfl(p, tt + 1);
        float pc = __shfl(p, tt + 2), pd = __shfl(p, tt + 3);
        int sa = __shfl(sidx, tt),     sb = __shfl(sidx, tt + 1);
        int sc = __shfl(sidx, tt + 2), sd = __shfl(sidx, tt + 3);
        float2 ha = ((const float2*)(h + (size_t)sa * 128))[lane];
        float2 hb = ((const float2*)(h + (size_t)sb * 128))[lane];
        float2 hc = ((const float2*)(h + (size_t)sc * 128))[lane];
        float2 hd = ((const float2*)(h + (size_t)sd * 128))[lane];
        accA0 = fmaf(pa, ha.x, accA0); accA1 = fmaf(pa, ha.y, accA1);
        accB0 = fmaf(pb, hb.x, accB0); accB1 = fmaf(pb, hb.y, accB1);
        accC0 = fmaf(pc, hc.x, accC0); accC1 = fmaf(pc, hc.y, accC1);
        accD0 = fmaf(pd, hd.x, accD0); accD1 = fmaf(pd, hd.y, accD1);
      }
      for (; tt < cnt; ++tt) {
        float pa = __shfl(p, tt); int sa = __shfl(sidx, tt);
        float2 ha = ((const float2*)(h + (size_t)sa * 128))[lane];
        accA0 = fmaf(pa, ha.x, accA0); accA1 = fmaf(pa, ha.y, accA1);
      }
    }
    for (int off = 32; off; off >>= 1) pacc += __shfl_xor(pacc, off);
    float inv = 1.0f / (eself + pacc + 1e-16f);
    float o0 = (accA0 + accB0) + (accC0 + accD0);
    float o1 = (accA1 + accB1) + (accC1 + accD1);
    o0 = fmaf(o0, inv, b2.x);
    o1 = fmaf(o1, inv, b2.y);
    o0 = o0 > 0.f ? o0 : 0.01f * o0;
    o1 = o1 > 0.f ? o1 : 0.01f * o1;
    float2 o2 = {o0, o1};
    ((float2*)(y + (size_t)i * 128))[lane] = o2;
    s0 += o0; s1 += o1;
    q0 = fmaf(o0, o0, q0); q1 = fmaf(o1, o1, q1);
  }
  __shared__ float red[4][4][64];
  red[0][w][lane] = s0; red[1][w][lane] = s1; red[2][w][lane] = q0; red[3][w][lane] = q1;
  __syncthreads();
  if (w == 0) {
    for (int ww = 1; ww < 4; ++ww) {
      s0 += red[0][ww][lane]; s1 += red[1][ww][lane];
      q0 += red[2][ww][lane]; q1 += red[3][ww][lane];
    }
    atomicAdd(&colsum[2 * lane], s0);
    atomicAdd(&colsum[2 * lane + 1], s1);
    atomicAdd(&colsumsq[2 * lane], q0);
    atomicAdd(&colsumsq[2 * lane + 1], q1);
  }
}

__global__ void k_bnfinal(const float* __restrict__ colsum, const float* __restrict__ colsumsq,
                          const float* __restrict__ g, const float* __restrict__ be,
                          float invN, float* __restrict__ scale, float* __restrict__ shift) {
  int c = threadIdx.x;  // 128
  float mu = colsum[c] * invN;
  float var = colsumsq[c] * invN - mu * mu;
  var = var > 0.f ? var : 0.f;
  float sc = g[c] * rsqrtf(var + 1e-5f);
  scale[c] = sc;
  shift[c] = be[c] - mu * sc;
}

__global__ void k_bnapply(const float4* __restrict__ yin, const float* __restrict__ scale,
                          const float* __restrict__ shift, float4* __restrict__ yout, int total4) {
  int i = blockIdx.x * blockDim.x + threadIdx.x;
  if (i >= total4) return;
  int c4 = i & 31;
  float4 v = yin[i];
  float4 sc = ((const float4*)scale)[c4];
  float4 sh = ((const float4*)shift)[c4];
  v.x = fmaf(v.x, sc.x, sh.x);
  v.y = fmaf(v.y, sc.y, sh.y);
  v.z = fmaf(v.z, sc.z, sh.z);
  v.w = fmaf(v.w, sc.w, sh.w);
  yout[i] = v;
}

extern "C" void kernel_launch(void* const* d_in, const int* in_sizes, int n_in,
                              void* d_out, int out_size, void* d_ws, size_t ws_size,
                              hipStream_t stream) {
  const float* x = (const float*)d_in[0];
  const int* eidx = (const int*)d_in[1];
  const float* ea = (const float*)d_in[3];
  const int H = 128;
  const int N = in_sizes[0] / H;
  const int E = in_sizes[1] / 2;
  const int* srcIdx = eidx;
  const int* dstIdx = eidx + E;

  char* ws = (char*)d_ws;
  size_t off = 0;
  auto alloc = [&](size_t bytes) -> void* {
    void* p = ws + off;
    off = (off + bytes + 255) & ~(size_t)255;
    return p;
  };
  Edge* edges = (Edge*)alloc((size_t)E * sizeof(Edge));
  int* srcs = (int*)alloc((size_t)E * sizeof(int));
  int* dsts = (int*)alloc((size_t)E * sizeof(int));
  float* pexp = (float*)alloc((size_t)E * sizeof(float));
  float* h = (float*)alloc((size_t)N * H * sizeof(float));
  float* y = (float*)alloc((size_t)N * H * sizeof(float));
  float* al_s = (float*)alloc((size_t)N * sizeof(float));
  float* al_d = (float*)alloc((size_t)N * sizeof(float));
  float* es = (float*)alloc((size_t)N * sizeof(float));
  int* deg = (int*)alloc((size_t)N * sizeof(int));
  int* start = (int*)alloc((size_t)(N + 1) * sizeof(int));
  int* cursor = (int*)alloc((size_t)N * sizeof(int));
  int* bsum = (int*)alloc(64 * sizeof(int));
  float* colsum = (float*)alloc(128 * sizeof(float));
  float* colsumsq = (float*)alloc(128 * sizeof(float));
  float* scale = (float*)alloc(128 * sizeof(float));
  float* shift = (float*)alloc(128 * sizeof(float));
  float* ea_sum = (float*)alloc(16 * sizeof(float));
  float* P = (float*)alloc(16 * sizeof(float));

  const int nb = (N + 1023) / 1024;  // 49 <= 64

  // ---- setup: sort edges by destination (CSR) ----
  hipMemsetAsync(deg, 0, (size_t)N * sizeof(int), stream);
  hipMemsetAsync(ea_sum, 0, 16 * sizeof(float), stream);
  k_hist<<<(E + 255) / 256, 256, 0, stream>>>(dstIdx, E, deg);
  k_ea_sum<<<256, 256, 0, stream>>>(ea, E, ea_sum);
  k_scan_a<<<nb, 1024, 0, stream>>>(deg, N, start, bsum);
  k_scan_b<<<1, 64, 0, stream>>>(bsum, nb, start, N);
  k_scan_c<<<(N + 255) / 256, 256, 0, stream>>>(start, bsum, N, cursor);
  k_scatter<<<(E + 255) / 256, 256, 0, stream>>>(srcIdx, dstIdx, ea, E, cursor, edges, srcs, dsts);
  k_initid<<<1, 128, 0, stream>>>(scale, shift);

  const float* X = x;
  for (int l = 0; l < 3; ++l) {
    const float* W = (const float*)d_in[4 + 8 * l + 0];
    const float* as = (const float*)d_in[4 + 8 * l + 1];
    const float* ad = (const float*)d_in[4 + 8 * l + 2];
    const float* We = (const float*)d_in[4 + 8 * l + 3];
    const float* ae = (const float*)d_in[4 + 8 * l + 4];
    const float* b = (const float*)d_in[4 + 8 * l + 5];
    const float* g = (const float*)d_in[4 + 8 * l + 6];
    const float* be = (const float*)d_in[4 + 8 * l + 7];

    hipMemsetAsync(colsum, 0, 128 * sizeof(float), stream);
    hipMemsetAsync(colsumsq, 0, 128 * sizeof(float), stream);
    k_param<<<1, 64, 0, stream>>>(We, ae, ea_sum, 1.0f / (float)E, P);
    k_gemm2<<<512, 256, 0, stream>>>(X, W, scale, shift, as, ad, P, h, al_s, al_d, es, N);
    k_alpha2<<<(E + 255) / 256, 256, 0, stream>>>((const float4*)edges, dsts, al_s, al_d, P,
                                                  pexp, E);
    k_agg3<<<2048, 256, 0, stream>>>(srcs, pexp, start, h, es, b, y, colsum, colsumsq, N);
    k_bnfinal<<<1, 128, 0, stream>>>(colsum, colsumsq, g, be, 1.0f / (float)N, scale, shift);
    X = y;
  }
  // final BN applied explicitly to produce the output
  k_bnapply<<<((N * 32) + 255) / 256, 256, 0, stream>>>((const float4*)y, scale, shift,
                                                        (float4*)d_out, N * 32);
}

// Round 4
// 783.355 us; speedup vs baseline: 1.7648x; 1.0853x over previous
//
#include <hip/hip_runtime.h>
#include <math.h>

// ---------------------------------------------------------------------------
// GAT x3 + BN on MI355X.
//   setup:  hist(dst) -> 3-phase parallel scan -> counting-sort edges (CSR).
//   layer:  P = We@a_edge + self logit
//           k_gemm2: h = BN(X)@W (W in LDS, 4x4 reg tile), writes h as BF16
//                    (halves gather lines + working set 25.6->12.8 MB so the
//                    L2-miss path stops being the limiter), fused al_s/al_d/es
//           k_alpha2: p[e] = exp(lrelu(als[src]+ald[dst]+ale))
//           k_agg4: per-node aggregate; edge meta via wave-uniform loads
//                   (readfirstlane'd CSR bounds -> scalar path, p identical in
//                   all lanes so denom needs NO reduction), 8-deep unrolled
//                   bf16 row gathers, + bias + lrelu + BN partials
//           k_bnfinal -> scale/shift consumed by NEXT layer's gemm staging;
//           k_bnapply only for the final output.
// R4: R3 showed k_agg pinned at ~1.5 TB/s L2-miss traffic (FETCH 190MB,
// VALU 8%) -> shrink miss traffic (bf16 h) + drop bpermute/xor-reduce.
// ---------------------------------------------------------------------------

struct __align__(16) Edge { int src; float e0, e1, e2; };

__device__ __forceinline__ unsigned short f2bf(float x) {
  unsigned u = __float_as_uint(x);
  unsigned r = (u + 0x7FFFu + ((u >> 16) & 1u)) >> 16;  // RNE
  return (unsigned short)r;
}

__global__ void k_hist(const int* __restrict__ dst, int E, int* __restrict__ deg) {
  int i = blockIdx.x * blockDim.x + threadIdx.x;
  if (i < E) atomicAdd(&deg[dst[i]], 1);
}

__global__ void k_ea_sum(const float* __restrict__ ea, int E, float* __restrict__ ea_sum) {
  float s0 = 0.f, s1 = 0.f, s2 = 0.f;
  for (int i = blockIdx.x * blockDim.x + threadIdx.x; i < E; i += gridDim.x * blockDim.x) {
    s0 += ea[i * 3 + 0]; s1 += ea[i * 3 + 1]; s2 += ea[i * 3 + 2];
  }
  for (int off = 32; off; off >>= 1) {
    s0 += __shfl_down(s0, off); s1 += __shfl_down(s1, off); s2 += __shfl_down(s2, off);
  }
  __shared__ float ls[3][4];
  int lane = threadIdx.x & 63, w = threadIdx.x >> 6;
  if (lane == 0) { ls[0][w] = s0; ls[1][w] = s1; ls[2][w] = s2; }
  __syncthreads();
  if (threadIdx.x == 0) {
    float t0 = 0.f, t1 = 0.f, t2 = 0.f;
    for (int ww = 0; ww < 4; ++ww) { t0 += ls[0][ww]; t1 += ls[1][ww]; t2 += ls[2][ww]; }
    atomicAdd(&ea_sum[0], t0); atomicAdd(&ea_sum[1], t1); atomicAdd(&ea_sum[2], t2);
  }
}

__device__ __forceinline__ int wave_incl_scan(int x, int lane) {
  for (int off = 1; off < 64; off <<= 1) {
    int t = __shfl_up(x, off);
    if (lane >= off) x += t;
  }
  return x;
}

__global__ __launch_bounds__(1024) void k_scan_a(const int* __restrict__ deg, int n,
                                                 int* __restrict__ start,
                                                 int* __restrict__ bsum) {
  __shared__ int wsum[16];
  int t = threadIdx.x, lane = t & 63, w = t >> 6;
  int i = blockIdx.x * 1024 + t;
  int v = (i < n) ? deg[i] : 0;
  int x = wave_incl_scan(v, lane);
  if (lane == 63) wsum[w] = x;
  __syncthreads();
  if (w == 0 && lane < 16) {
    int s = wsum[lane];
    for (int off = 1; off < 16; off <<= 1) {
      int u = __shfl_up(s, off);
      if (lane >= off) s += u;
    }
    wsum[lane] = s;
  }
  __syncthreads();
  int woff = w ? wsum[w - 1] : 0;
  if (i < n) start[i] = x - v + woff;
  if (t == 1023) bsum[blockIdx.x] = wsum[15];
}

__global__ void k_scan_b(int* __restrict__ bsum, int nb, int* __restrict__ start, int n) {
  int lane = threadIdx.x;  // 64
  int v = (lane < nb) ? bsum[lane] : 0;
  int x = wave_incl_scan(v, lane);
  if (lane < nb) bsum[lane] = x - v;
  if (lane == nb - 1) start[n] = x;
}

__global__ void k_scan_c(int* __restrict__ start, const int* __restrict__ bsum, int n,
                         int* __restrict__ cursor) {
  int i = blockIdx.x * blockDim.x + threadIdx.x;
  if (i < n) {
    int s = start[i] + bsum[i >> 10];
    start[i] = s;
    cursor[i] = s;
  }
}

__global__ void k_scatter(const int* __restrict__ src, const int* __restrict__ dst,
                          const float* __restrict__ ea, int E,
                          int* __restrict__ cursor, Edge* __restrict__ edges,
                          int* __restrict__ srcs, int* __restrict__ dsts) {
  int i = blockIdx.x * blockDim.x + threadIdx.x;
  if (i >= E) return;
  int d = dst[i];
  int pos = atomicAdd(&cursor[d], 1);
  Edge e;
  int s = src[i];
  e.src = s;
  e.e0 = ea[i * 3 + 0]; e.e1 = ea[i * 3 + 1]; e.e2 = ea[i * 3 + 2];
  edges[pos] = e;
  srcs[pos] = s;
  dsts[pos] = d;
}

__global__ void k_initid(float* __restrict__ sc, float* __restrict__ sh) {
  int c = threadIdx.x;  // 128
  sc[c] = 1.f; sh[c] = 0.f;
}

__global__ void k_param(const float* __restrict__ We, const float* __restrict__ ae,
                        const float* __restrict__ ea_sum, float invE, float* __restrict__ P) {
  int lane = threadIdx.x;  // 64
  float a0 = ae[lane], a1 = ae[64 + lane];
  float p0 = We[0 * 128 + lane] * a0 + We[0 * 128 + 64 + lane] * a1;
  float p1 = We[1 * 128 + lane] * a0 + We[1 * 128 + 64 + lane] * a1;
  float p2 = We[2 * 128 + lane] * a0 + We[2 * 128 + 64 + lane] * a1;
  for (int off = 32; off; off >>= 1) {
    p0 += __shfl_down(p0, off); p1 += __shfl_down(p1, off); p2 += __shfl_down(p2, off);
  }
  if (lane == 0) {
    P[0] = p0; P[1] = p1; P[2] = p2;
    P[3] = ea_sum[0] * invE * p0 + ea_sum[1] * invE * p1 + ea_sum[2] * invE * p2;
  }
}

// h[N,128] = (X*bnsc+bnsh) @ W, stored as bf16 rows (256 B).  W in LDS,
// 32-row tiles, 4 rows x 4 cols per thread.  Fused al_s/al_d/es epilogue.
__global__ __launch_bounds__(256) void k_gemm2(
    const float* __restrict__ X, const float* __restrict__ Wm,
    const float* __restrict__ bnsc, const float* __restrict__ bnsh,
    const float* __restrict__ as, const float* __restrict__ ad,
    const float* __restrict__ P,
    unsigned* __restrict__ hb, float* __restrict__ al_s, float* __restrict__ al_d,
    float* __restrict__ es, int n) {
  __shared__ float wl[128 * 128];
  __shared__ float xs[32 * 128];
  int t = threadIdx.x;
  for (int i = t; i < 4096; i += 256) ((float4*)wl)[i] = ((const float4*)Wm)[i];
  int c32 = t & 31;
  int c4 = c32 << 2;
  int rq = t >> 5;
  int lane = t & 63;
  float4 av_s = *(const float4*)(as + c4);
  float4 av_d = *(const float4*)(ad + c4);
  float cself = P[3];
  int ntiles = (n + 31) >> 5;
  for (int tile = blockIdx.x; tile < ntiles; tile += gridDim.x) {
    int r0 = tile << 5;
    __syncthreads();
    for (int i = t; i < 1024; i += 256) {
      int rr = i >> 5, cc = i & 31;
      int g = r0 + rr;
      float4 v;
      if (g < n) {
        v = ((const float4*)(X + (size_t)g * 128))[cc];
        float4 sc = ((const float4*)bnsc)[cc];
        float4 sh = ((const float4*)bnsh)[cc];
        v.x = fmaf(v.x, sc.x, sh.x); v.y = fmaf(v.y, sc.y, sh.y);
        v.z = fmaf(v.z, sc.z, sh.z); v.w = fmaf(v.w, sc.w, sh.w);
      } else { v.x = v.y = v.z = v.w = 0.f; }
      ((float4*)xs)[i] = v;
    }
    __syncthreads();
    float4 acc[4];
    for (int r = 0; r < 4; ++r) { acc[r].x = acc[r].y = acc[r].z = acc[r].w = 0.f; }
    const float* xr = xs + (rq << 2) * 128;
#pragma unroll 4
    for (int k = 0; k < 128; ++k) {
      float4 w4 = ((const float4*)wl)[(k << 5) + c32];
#pragma unroll
      for (int r = 0; r < 4; ++r) {
        float xv = xr[r * 128 + k];
        acc[r].x = fmaf(xv, w4.x, acc[r].x);
        acc[r].y = fmaf(xv, w4.y, acc[r].y);
        acc[r].z = fmaf(xv, w4.z, acc[r].z);
        acc[r].w = fmaf(xv, w4.w, acc[r].w);
      }
    }
    int gbase = r0 + (rq << 2);
#pragma unroll
    for (int r = 0; r < 4; ++r) {
      int g = gbase + r;
      float4 o = acc[r];
      if (g < n) {
        unsigned u01 = ((unsigned)f2bf(o.y) << 16) | (unsigned)f2bf(o.x);
        unsigned u23 = ((unsigned)f2bf(o.w) << 16) | (unsigned)f2bf(o.z);
        uint2 uu = {u01, u23};
        *(uint2*)(hb + (size_t)g * 64 + (c32 << 1)) = uu;
      }
      float ps = o.x * av_s.x + o.y * av_s.y + o.z * av_s.z + o.w * av_s.w;
      float pd = o.x * av_d.x + o.y * av_d.y + o.z * av_d.z + o.w * av_d.w;
      for (int off = 16; off; off >>= 1) {
        ps += __shfl_xor(ps, off);
        pd += __shfl_xor(pd, off);
      }
      if ((lane & 31) == 0 && g < n) {
        al_s[g] = ps; al_d[g] = pd;
        float a = ps + pd + cself;
        a = a > 0.f ? a : 0.2f * a;
        es[g] = __expf(a);
      }
    }
  }
}

__global__ __launch_bounds__(256) void k_alpha2(const float4* __restrict__ edges,
                                                const int* __restrict__ dsts,
                                                const float* __restrict__ al_s,
                                                const float* __restrict__ al_d,
                                                const float* __restrict__ P,
                                                float* __restrict__ pexp, int E) {
  int i = blockIdx.x * blockDim.x + threadIdx.x;
  if (i >= E) return;
  float4 ef = edges[i];
  int s = __float_as_int(ef.x);
  float a = al_s[s] + al_d[dsts[i]] + ef.y * P[0] + ef.z * P[1] + ef.w * P[2];
  a = a > 0.f ? a : 0.2f * a;
  pexp[i] = __expf(a);
}

// one wave per node.  Edge meta (srcs, pexp) via wave-uniform loads; p is
// identical in all lanes so the denominator needs no reduction.  bf16 row
// gathers (lane reads 4 B = 2 features), 8-deep unroll, 4 acc pairs.
__global__ __launch_bounds__(256) void k_agg4(const int* __restrict__ srcs,
                                              const float* __restrict__ pexp,
                                              const int* __restrict__ start,
                                              const unsigned* __restrict__ hb,
                                              const float* __restrict__ es,
                                              const float* __restrict__ bias,
                                              float* __restrict__ y,
                                              float* __restrict__ colsum,
                                              float* __restrict__ colsumsq, int n) {
  int lane = threadIdx.x & 63;
  int w = threadIdx.x >> 6;
  int gw = (blockIdx.x * blockDim.x + threadIdx.x) >> 6;
  int nw = (gridDim.x * blockDim.x) >> 6;
  float2 b2 = ((const float2*)bias)[lane];
  float s0 = 0.f, s1 = 0.f, q0 = 0.f, q1 = 0.f;
  for (int i = gw; i < n; i += nw) {
    int e0 = __builtin_amdgcn_readfirstlane(start[i]);
    int e1 = __builtin_amdgcn_readfirstlane(start[i + 1]);
    float eself = es[i];
    unsigned hv = hb[(size_t)i * 64 + lane];
    float hx = __uint_as_float(hv << 16);
    float hy = __uint_as_float(hv & 0xFFFF0000u);
    float aX0 = eself * hx, aY0 = eself * hy;
    float aX1 = 0.f, aY1 = 0.f, aX2 = 0.f, aY2 = 0.f, aX3 = 0.f, aY3 = 0.f;
    float pacc = 0.f;
    int e = e0;
    for (; e + 8 <= e1; e += 8) {
      int sv[8]; float pv[8]; unsigned gv[8];
#pragma unroll
      for (int k = 0; k < 8; ++k) sv[k] = srcs[e + k];
#pragma unroll
      for (int k = 0; k < 8; ++k) pv[k] = pexp[e + k];
#pragma unroll
      for (int k = 0; k < 8; ++k) gv[k] = hb[(size_t)sv[k] * 64 + lane];
#pragma unroll
      for (int k = 0; k < 8; ++k) {
        float gx = __uint_as_float(gv[k] << 16);
        float gy = __uint_as_float(gv[k] & 0xFFFF0000u);
        pacc += pv[k];
        if ((k & 3) == 0) { aX0 = fmaf(pv[k], gx, aX0); aY0 = fmaf(pv[k], gy, aY0); }
        else if ((k & 3) == 1) { aX1 = fmaf(pv[k], gx, aX1); aY1 = fmaf(pv[k], gy, aY1); }
        else if ((k & 3) == 2) { aX2 = fmaf(pv[k], gx, aX2); aY2 = fmaf(pv[k], gy, aY2); }
        else { aX3 = fmaf(pv[k], gx, aX3); aY3 = fmaf(pv[k], gy, aY3); }
      }
    }
    for (; e < e1; ++e) {
      int sv = srcs[e];
      float pv = pexp[e];
      unsigned gv = hb[(size_t)sv * 64 + lane];
      float gx = __uint_as_float(gv << 16);
      float gy = __uint_as_float(gv & 0xFFFF0000u);
      pacc += pv;
      aX0 = fmaf(pv, gx, aX0); aY0 = fmaf(pv, gy, aY0);
    }
    float inv = 1.0f / (eself + pacc + 1e-16f);
    float o0 = (aX0 + aX1) + (aX2 + aX3);
    float o1 = (aY0 + aY1) + (aY2 + aY3);
    o0 = fmaf(o0, inv, b2.x);
    o1 = fmaf(o1, inv, b2.y);
    o0 = o0 > 0.f ? o0 : 0.01f * o0;
    o1 = o1 > 0.f ? o1 : 0.01f * o1;
    float2 o2 = {o0, o1};
    ((float2*)(y + (size_t)i * 128))[lane] = o2;
    s0 += o0; s1 += o1;
    q0 = fmaf(o0, o0, q0); q1 = fmaf(o1, o1, q1);
  }
  __shared__ float red[4][4][64];
  red[0][w][lane] = s0; red[1][w][lane] = s1; red[2][w][lane] = q0; red[3][w][lane] = q1;
  __syncthreads();
  if (w == 0) {
    for (int ww = 1; ww < 4; ++ww) {
      s0 += red[0][ww][lane]; s1 += red[1][ww][lane];
      q0 += red[2][ww][lane]; q1 += red[3][ww][lane];
    }
    atomicAdd(&colsum[2 * lane], s0);
    atomicAdd(&colsum[2 * lane + 1], s1);
    atomicAdd(&colsumsq[2 * lane], q0);
    atomicAdd(&colsumsq[2 * lane + 1], q1);
  }
}

__global__ void k_bnfinal(const float* __restrict__ colsum, const float* __restrict__ colsumsq,
                          const float* __restrict__ g, const float* __restrict__ be,
                          float invN, float* __restrict__ scale, float* __restrict__ shift) {
  int c = threadIdx.x;  // 128
  float mu = colsum[c] * invN;
  float var = colsumsq[c] * invN - mu * mu;
  var = var > 0.f ? var : 0.f;
  float sc = g[c] * rsqrtf(var + 1e-5f);
  scale[c] = sc;
  shift[c] = be[c] - mu * sc;
}

__global__ void k_bnapply(const float4* __restrict__ yin, const float* __restrict__ scale,
                          const float* __restrict__ shift, float4* __restrict__ yout, int total4) {
  int i = blockIdx.x * blockDim.x + threadIdx.x;
  if (i >= total4) return;
  int c4 = i & 31;
  float4 v = yin[i];
  float4 sc = ((const float4*)scale)[c4];
  float4 sh = ((const float4*)shift)[c4];
  v.x = fmaf(v.x, sc.x, sh.x);
  v.y = fmaf(v.y, sc.y, sh.y);
  v.z = fmaf(v.z, sc.z, sh.z);
  v.w = fmaf(v.w, sc.w, sh.w);
  yout[i] = v;
}

extern "C" void kernel_launch(void* const* d_in, const int* in_sizes, int n_in,
                              void* d_out, int out_size, void* d_ws, size_t ws_size,
                              hipStream_t stream) {
  const float* x = (const float*)d_in[0];
  const int* eidx = (const int*)d_in[1];
  const float* ea = (const float*)d_in[3];
  const int H = 128;
  const int N = in_sizes[0] / H;
  const int E = in_sizes[1] / 2;
  const int* srcIdx = eidx;
  const int* dstIdx = eidx + E;

  char* ws = (char*)d_ws;
  size_t off = 0;
  auto alloc = [&](size_t bytes) -> void* {
    void* p = ws + off;
    off = (off + bytes + 255) & ~(size_t)255;
    return p;
  };
  Edge* edges = (Edge*)alloc((size_t)E * sizeof(Edge));
  int* srcs = (int*)alloc((size_t)E * sizeof(int));
  int* dsts = (int*)alloc((size_t)E * sizeof(int));
  float* pexp = (float*)alloc((size_t)E * sizeof(float));
  unsigned* hb = (unsigned*)alloc((size_t)N * 64 * sizeof(unsigned));  // bf16 h
  float* y = (float*)alloc((size_t)N * H * sizeof(float));
  float* al_s = (float*)alloc((size_t)N * sizeof(float));
  float* al_d = (float*)alloc((size_t)N * sizeof(float));
  float* es = (float*)alloc((size_t)N * sizeof(float));
  int* deg = (int*)alloc((size_t)N * sizeof(int));
  int* start = (int*)alloc((size_t)(N + 1) * sizeof(int));
  int* cursor = (int*)alloc((size_t)N * sizeof(int));
  int* bsum = (int*)alloc(64 * sizeof(int));
  float* colsum = (float*)alloc(128 * sizeof(float));
  float* colsumsq = (float*)alloc(128 * sizeof(float));
  float* scale = (float*)alloc(128 * sizeof(float));
  float* shift = (float*)alloc(128 * sizeof(float));
  float* ea_sum = (float*)alloc(16 * sizeof(float));
  float* P = (float*)alloc(16 * sizeof(float));

  const int nb = (N + 1023) / 1024;  // <= 64

  // ---- setup: sort edges by destination (CSR) ----
  hipMemsetAsync(deg, 0, (size_t)N * sizeof(int), stream);
  hipMemsetAsync(ea_sum, 0, 16 * sizeof(float), stream);
  k_hist<<<(E + 255) / 256, 256, 0, stream>>>(dstIdx, E, deg);
  k_ea_sum<<<256, 256, 0, stream>>>(ea, E, ea_sum);
  k_scan_a<<<nb, 1024, 0, stream>>>(deg, N, start, bsum);
  k_scan_b<<<1, 64, 0, stream>>>(bsum, nb, start, N);
  k_scan_c<<<(N + 255) / 256, 256, 0, stream>>>(start, bsum, N, cursor);
  k_scatter<<<(E + 255) / 256, 256, 0, stream>>>(srcIdx, dstIdx, ea, E, cursor, edges, srcs, dsts);
  k_initid<<<1, 128, 0, stream>>>(scale, shift);

  const float* X = x;
  for (int l = 0; l < 3; ++l) {
    const float* W = (const float*)d_in[4 + 8 * l + 0];
    const float* as = (const float*)d_in[4 + 8 * l + 1];
    const float* ad = (const float*)d_in[4 + 8 * l + 2];
    const float* We = (const float*)d_in[4 + 8 * l + 3];
    const float* ae = (const float*)d_in[4 + 8 * l + 4];
    const float* b = (const float*)d_in[4 + 8 * l + 5];
    const float* g = (const float*)d_in[4 + 8 * l + 6];
    const float* be = (const float*)d_in[4 + 8 * l + 7];

    hipMemsetAsync(colsum, 0, 128 * sizeof(float), stream);
    hipMemsetAsync(colsumsq, 0, 128 * sizeof(float), stream);
    k_param<<<1, 64, 0, stream>>>(We, ae, ea_sum, 1.0f / (float)E, P);
    k_gemm2<<<512, 256, 0, stream>>>(X, W, scale, shift, as, ad, P, hb, al_s, al_d, es, N);
    k_alpha2<<<(E + 255) / 256, 256, 0, stream>>>((const float4*)edges, dsts, al_s, al_d, P,
                                                  pexp, E);
    k_agg4<<<2048, 256, 0, stream>>>(srcs, pexp, start, hb, es, b, y, colsum, colsumsq, N);
    k_bnfinal<<<1, 128, 0, stream>>>(colsum, colsumsq, g, be, 1.0f / (float)N, scale, shift);
    X = y;
  }
  k_bnapply<<<((N * 32) + 255) / 256, 256, 0, stream>>>((const float4*)y, scale, shift,
                                                        (float4*)d_out, N * 32);
}